// Round 8
// baseline (73.776 us; speedup 1.0000x reference)
//
#include <hip/hip_runtime.h>

// ---------------------------------------------------------------------------
// TOD -> sky map scatter (map-making P^T), B=4 batches, 3 Stokes (I,Q,U).
// out[b][p][k] = (sum_{s: pix[s]==p} tod[b][s] * w[s][k]) / cov[p]
//
// R1: direct global atomics  -> 1178 us (fabric atomics, 732 MB writes)
// R2: counting-sort + gather -> 200 us  (accum gather 516 MB fetch)
// R3: payload sort + stream  -> 184 us  (ds_add_f32-bound accum)
// R5: accum in-LDS sort + reg accumulate -> 82 us (reorder dominant)
// R7: 16B bf16 records, 1 scattered store/sample -> 73 us (reorder 53 us,
//     WRITE_SIZE 60 MB = partial-line write-backs)
// R8: reorder writes in LOCALLY SORTED order (runs of ~7.6 records) with
//     coarser buckets (NB=256, BW=768 pixels) -> full-line coalesced stores.
// ---------------------------------------------------------------------------

constexpr int NB   = 256;    // buckets
constexpr int BW   = 768;    // pixels per bucket (npix = NB*BW = 196608)
constexpr int NBLK = 1024;   // chunking blocks for hist/reorder
constexpr int TILE = 2048;   // records per tile (reorder chunk & accum tile)

// hist2d layout: [NBLK][NB]

__device__ __forceinline__ unsigned f2bf(float f) {
    unsigned u = __float_as_uint(f);
    unsigned r = ((u >> 16) & 1u) + 0x7fffu;   // round to nearest even
    return (u + r) >> 16;
}
__device__ __forceinline__ float bf_lo(unsigned u) {
    return __uint_as_float(u << 16);
}
__device__ __forceinline__ float bf_hi(unsigned u) {
    return __uint_as_float(u & 0xffff0000u);
}

// ---------------- sort infrastructure ----------------

__global__ __launch_bounds__(512)
void hist_kernel(const int* __restrict__ pix, int S, int chunk,
                 int* __restrict__ hist2d) {
    __shared__ int lh[NB];
    for (int t = threadIdx.x; t < NB; t += blockDim.x) lh[t] = 0;
    __syncthreads();
    const int beg = blockIdx.x * chunk;
    const int end = min(S, beg + chunk);
    for (int j = beg + threadIdx.x; j < end; j += blockDim.x)
        atomicAdd(&lh[pix[j] / BW], 1);
    __syncthreads();
    for (int t = threadIdx.x; t < NB; t += blockDim.x)
        hist2d[(size_t)blockIdx.x * NB + t] = lh[t];   // coalesced
}

// one block per bucket: exclusive scan of its NBLK per-block counts
__global__ __launch_bounds__(NBLK)
void scan_blocks_kernel(int* __restrict__ hist2d,
                        int* __restrict__ btotal) {
    __shared__ int sc[NBLK];
    const int bkt = blockIdx.x, tid = threadIdx.x;
    const int v = hist2d[(size_t)tid * NB + bkt];
    sc[tid] = v;
    __syncthreads();
    for (int off = 1; off < NBLK; off <<= 1) {
        int x = (tid >= off) ? sc[tid - off] : 0;
        __syncthreads();
        sc[tid] += x;
        __syncthreads();
    }
    hist2d[(size_t)tid * NB + bkt] = sc[tid] - v;   // exclusive within bucket
    if (tid == NBLK - 1) btotal[bkt] = sc[tid];
}

// single block: exclusive scan of NB bucket totals
__global__ __launch_bounds__(NB)
void scan_buckets_kernel(const int* __restrict__ btotal,
                         int* __restrict__ bbase, int S) {
    __shared__ int sc[NB];
    const int tid = threadIdx.x;
    const int v = btotal[tid];
    sc[tid] = v;
    __syncthreads();
    for (int off = 1; off < NB; off <<= 1) {
        int x = (tid >= off) ? sc[tid - off] : 0;
        __syncthreads();
        sc[tid] += x;
        __syncthreads();
    }
    bbase[tid] = sc[tid] - v;
    if (tid == NB - 1) bbase[NB] = sc[tid];
}

// ---------------- R8 reorder: local counting sort, coalesced record writes
// record = {w0|w1, w2|lpix, t0|t1, t2|t3} packed bf16, 16 B
__global__ __launch_bounds__(512)
void reorder_sorted_kernel(const float* __restrict__ tod,     // [4][S]
                           const float* __restrict__ weights, // [S][3]
                           const int* __restrict__ pix,       // [S]
                           int S, int chunk,
                           const int* __restrict__ hist2d,
                           const int* __restrict__ bbase,
                           uint4* __restrict__ rec) {         // [S]
    __shared__ uint4          lrec[TILE];      // 32 KB
    __shared__ unsigned short lbk[TILE];       //  4 KB (bucket id)
    __shared__ unsigned short lidx[TILE];      //  4 KB (sorted -> staged)
    __shared__ int            lcur[NB];
    __shared__ int            lstart[NB];
    __shared__ int            lbase[NB];

    const int blk = blockIdx.x;
    const int beg = blk * chunk;
    const int end = min(S, beg + chunk);
    const int n = end - beg;

    if (threadIdx.x < NB) {
        lcur[threadIdx.x] = 0;
        lbase[threadIdx.x] = bbase[threadIdx.x]
                           + hist2d[(size_t)blk * NB + threadIdx.x];
    }
    __syncthreads();

    // stage records into LDS + build histogram
    for (int jj = threadIdx.x; jj < n; jj += blockDim.x) {
        const int j = beg + jj;
        const int p = pix[j];
        const int bkt = p / BW;
        const int lp  = p - bkt * BW;
        const float w0 = weights[3 * j + 0];
        const float w1 = weights[3 * j + 1];
        const float w2 = weights[3 * j + 2];
        const float t0 = tod[(size_t)0 * S + j];
        const float t1 = tod[(size_t)1 * S + j];
        const float t2 = tod[(size_t)2 * S + j];
        const float t3 = tod[(size_t)3 * S + j];
        uint4 v;
        v.x = f2bf(w0) | (f2bf(w1) << 16);
        v.y = f2bf(w2) | ((unsigned)lp << 16);
        v.z = f2bf(t0) | (f2bf(t1) << 16);
        v.w = f2bf(t2) | (f2bf(t3) << 16);
        lrec[jj] = v;
        lbk[jj] = (unsigned short)bkt;
        atomicAdd(&lcur[bkt], 1);
    }
    __syncthreads();

    // wave 0: exclusive scan of NB=256 counts (4 bins/lane + shfl scan)
    if (threadIdx.x < 64) {
        const int i0 = threadIdx.x * 4;
        const int a0 = lcur[i0], a1 = lcur[i0 + 1];
        const int a2 = lcur[i0 + 2], a3 = lcur[i0 + 3];
        const int t1 = a0 + a1, t2 = t1 + a2, t3 = t2 + a3;
        int x = t3;
        #pragma unroll
        for (int off = 1; off < 64; off <<= 1) {
            const int y = __shfl_up(x, off, 64);
            if ((int)threadIdx.x >= off) x += y;
        }
        const int base = x - t3;
        lstart[i0]     = base;
        lstart[i0 + 1] = base + a0;
        lstart[i0 + 2] = base + t1;
        lstart[i0 + 3] = base + t2;
        lcur[i0]     = base;
        lcur[i0 + 1] = base + a0;
        lcur[i0 + 2] = base + t1;
        lcur[i0 + 3] = base + t2;
    }
    __syncthreads();

    // rank: build sorted -> staged permutation
    for (int jj = threadIdx.x; jj < n; jj += blockDim.x) {
        const int r = atomicAdd(&lcur[lbk[jj]], 1);
        lidx[r] = (unsigned short)jj;
    }
    __syncthreads();

    // write in sorted order: contiguous dst within each bucket run
    for (int r = threadIdx.x; r < n; r += blockDim.x) {
        const int jj = lidx[r];
        const int bkt = lbk[jj];
        const int dst = lbase[bkt] + (r - lstart[bkt]);
        rec[dst] = lrec[jj];
    }
}

// one block (1024 threads) per bucket (768 pixels). Per tile of <=2048:
//   stage records in LDS -> 768-bin counting sort (int LDS atomics) ->
//   thread (l=tid&255, q=tid>>8) walks pixels {l, l+256, l+512}, f32 regs.
__global__ __launch_bounds__(1024)
void accum_sort_kernel(const uint4* __restrict__ rec,    // [S]
                       const float* __restrict__ cov,    // [npix]
                       const int* __restrict__ bbase,    // [NB+1]
                       float* __restrict__ out,          // [4][npix][3]
                       int npix) {
    __shared__ uint4          lrec[TILE];      // 32 KB
    __shared__ unsigned short lpx[TILE];       //  4 KB (local pixel 0..767)
    __shared__ unsigned short lidx[TILE];      //  4 KB
    __shared__ int            start[BW + 1];   //  ~3 KB
    __shared__ int            cur[BW];         //  3 KB

    const int bkt = blockIdx.x;
    const int beg = bbase[bkt], end = bbase[bkt + 1];
    const int l = threadIdx.x & 255;
    const int q = threadIdx.x >> 8;            // wave-uniform
    float s00 = 0.f, s01 = 0.f, s02 = 0.f;
    float s10 = 0.f, s11 = 0.f, s12 = 0.f;
    float s20 = 0.f, s21 = 0.f, s22 = 0.f;

    for (int tbeg = beg; tbeg < end; tbeg += TILE) {
        const int n = min(TILE, end - tbeg);

        for (int t = threadIdx.x; t < BW; t += blockDim.x) cur[t] = 0;
        __syncthreads();
        for (int j = threadIdx.x; j < n; j += blockDim.x) {
            const uint4 r = rec[(size_t)(tbeg + j)];
            lrec[j] = r;
            const int lp = (int)(r.y >> 16);
            lpx[j] = (unsigned short)lp;
            atomicAdd(&cur[lp], 1);
        }
        __syncthreads();

        // wave 0: exclusive scan of BW=768 counts (12 bins/lane + shfl scan)
        if (threadIdx.x < 64) {
            const int i0 = threadIdx.x * 12;
            int v[12], pre[12], run = 0;
            #pragma unroll
            for (int k = 0; k < 12; ++k) {
                v[k] = cur[i0 + k]; pre[k] = run; run += v[k];
            }
            int x = run;
            #pragma unroll
            for (int off = 1; off < 64; off <<= 1) {
                const int y = __shfl_up(x, off, 64);
                if ((int)threadIdx.x >= off) x += y;
            }
            const int base = x - run;
            #pragma unroll
            for (int k = 0; k < 12; ++k) {
                start[i0 + k] = base + pre[k];
                cur[i0 + k]   = base + pre[k];
            }
            if (threadIdx.x == 63) start[BW] = base + run;
        }
        __syncthreads();

        for (int j = threadIdx.x; j < n; j += blockDim.x) {
            const int r = atomicAdd(&cur[lpx[j]], 1);
            lidx[r] = (unsigned short)j;
        }
        __syncthreads();

        // three statically-unrolled run walks (pixels l, l+256, l+512)
        {
            const int rb = start[l], re = start[l + 1];
            for (int j = rb; j < re; ++j) {
                const int i = lidx[j];
                const uint4 r = lrec[i];
                const float tq = (q == 0) ? bf_lo(r.z) : (q == 1) ? bf_hi(r.z)
                               : (q == 2) ? bf_lo(r.w) : bf_hi(r.w);
                s00 += tq * bf_lo(r.x);
                s01 += tq * bf_hi(r.x);
                s02 += tq * bf_lo(r.y);
            }
        }
        {
            const int rb = start[l + 256], re = start[l + 257];
            for (int j = rb; j < re; ++j) {
                const int i = lidx[j];
                const uint4 r = lrec[i];
                const float tq = (q == 0) ? bf_lo(r.z) : (q == 1) ? bf_hi(r.z)
                               : (q == 2) ? bf_lo(r.w) : bf_hi(r.w);
                s10 += tq * bf_lo(r.x);
                s11 += tq * bf_hi(r.x);
                s12 += tq * bf_lo(r.y);
            }
        }
        {
            const int rb = start[l + 512], re = start[l + 513];
            for (int j = rb; j < re; ++j) {
                const int i = lidx[j];
                const uint4 r = lrec[i];
                const float tq = (q == 0) ? bf_lo(r.z) : (q == 1) ? bf_hi(r.z)
                               : (q == 2) ? bf_lo(r.w) : bf_hi(r.w);
                s20 += tq * bf_lo(r.x);
                s21 += tq * bf_hi(r.x);
                s22 += tq * bf_lo(r.y);
            }
        }
        __syncthreads();
    }

    // fused coverage normalize + coalesced store (3 pixel groups)
    {
        const int p = bkt * BW + l;
        const float rc = 1.0f / cov[p];
        const size_t o = ((size_t)q * npix + p) * 3;
        out[o + 0] = s00 * rc; out[o + 1] = s01 * rc; out[o + 2] = s02 * rc;
    }
    {
        const int p = bkt * BW + 256 + l;
        const float rc = 1.0f / cov[p];
        const size_t o = ((size_t)q * npix + p) * 3;
        out[o + 0] = s10 * rc; out[o + 1] = s11 * rc; out[o + 2] = s12 * rc;
    }
    {
        const int p = bkt * BW + 512 + l;
        const float rc = 1.0f / cov[p];
        const size_t o = ((size_t)q * npix + p) * 3;
        out[o + 0] = s20 * rc; out[o + 1] = s21 * rc; out[o + 2] = s22 * rc;
    }
}

// ---------------- generic fallback: direct atomics -------------------------

__global__ void zero_out_kernel(float4* __restrict__ out, int n4) {
    int i = blockIdx.x * blockDim.x + threadIdx.x;
    int stride = gridDim.x * blockDim.x;
    for (; i < n4; i += stride) out[i] = make_float4(0.f, 0.f, 0.f, 0.f);
}

__global__ void scatter_kernel(const float* __restrict__ tod,
                               const float* __restrict__ weights,
                               const int*   __restrict__ pix,
                               float* __restrict__ out,
                               int S, int npix, int B) {
    int i = blockIdx.x * blockDim.x + threadIdx.x;
    int stride = gridDim.x * blockDim.x;
    const size_t bstride = (size_t)npix * 3;
    for (int s = i; s < S; s += stride) {
        const int p = pix[s];
        const float w0 = weights[3 * s + 0];
        const float w1 = weights[3 * s + 1];
        const float w2 = weights[3 * s + 2];
        float* o = out + (size_t)p * 3;
        for (int b = 0; b < B; ++b) {
            const float t = tod[(size_t)b * S + s];
            float* ob = o + (size_t)b * bstride;
            atomicAdd(ob + 0, t * w0);
            atomicAdd(ob + 1, t * w1);
            atomicAdd(ob + 2, t * w2);
        }
    }
}

__global__ void normalize_kernel(float* __restrict__ out,
                                 const float* __restrict__ cov,
                                 int npix, int B) {
    int i = blockIdx.x * blockDim.x + threadIdx.x;
    int stride = gridDim.x * blockDim.x;
    const int total = B * npix;
    for (; i < total; i += stride) {
        const int p = i % npix;
        const float c = cov[p];
        float* o = out + (size_t)i * 3;
        o[0] /= c; o[1] /= c; o[2] /= c;
    }
}

// ---------------- launch ----------------

extern "C" void kernel_launch(void* const* d_in, const int* in_sizes, int n_in,
                              void* d_out, int out_size, void* d_ws, size_t ws_size,
                              hipStream_t stream) {
    const float* tod     = (const float*)d_in[0];   // [B][S]
    const float* weights = (const float*)d_in[1];   // [S][3]
    const float* cov     = (const float*)d_in[2];   // [NPIX]
    const int*   pix     = (const int*)d_in[3];     // [S]
    float* out = (float*)d_out;                     // [B][NPIX][3]

    const int S    = in_sizes[3];
    const int npix = in_sizes[2];
    const int B    = in_sizes[0] / S;

    const size_t meta_ints  = (size_t)NB * NBLK + NB + (NB + 1);
    const size_t meta_bytes = ((meta_ints * sizeof(int)) + 63) & ~(size_t)63;
    const size_t need_rec   = meta_bytes + (size_t)S * 16;

    const int chunk = (S + NBLK - 1) / NBLK;

    if (B == 4 && npix == NB * BW && chunk <= TILE && ws_size >= need_rec) {
        int* hist2d = (int*)d_ws;                   // [NBLK][NB]
        int* btotal = hist2d + (size_t)NB * NBLK;
        int* bbase  = btotal + NB;
        uint4* rec  = (uint4*)((char*)d_ws + meta_bytes);

        hist_kernel<<<NBLK, 512, 0, stream>>>(pix, S, chunk, hist2d);
        scan_blocks_kernel<<<NB, NBLK, 0, stream>>>(hist2d, btotal);
        scan_buckets_kernel<<<1, NB, 0, stream>>>(btotal, bbase, S);
        reorder_sorted_kernel<<<NBLK, 512, 0, stream>>>(tod, weights, pix, S,
                                                        chunk, hist2d, bbase, rec);
        accum_sort_kernel<<<NB, 1024, 0, stream>>>(rec, cov, bbase, out, npix);
        return;
    }

    // ---- generic fallback ----
    const int block = 256;
    {
        const int n4 = out_size / 4;
        int grid = min((n4 + block - 1) / block, 2048);
        zero_out_kernel<<<grid, block, 0, stream>>>((float4*)out, n4);
    }
    {
        int grid = min((S + block - 1) / block, 4096);
        scatter_kernel<<<grid, block, 0, stream>>>(tod, weights, pix, out, S, npix, B);
    }
    {
        const int total = B * npix;
        int grid = min((total + block - 1) / block, 2048);
        normalize_kernel<<<grid, block, 0, stream>>>(out, cov, npix, B);
    }
}

// Round 9
// 69.874 us; speedup vs baseline: 1.0558x; 1.0558x over previous
//
#include <hip/hip_runtime.h>

// ---------------------------------------------------------------------------
// TOD -> sky map scatter (map-making P^T), B=4 batches, 3 Stokes (I,Q,U).
// out[b][p][k] = (sum_{s: pix[s]==p} tod[b][s] * w[s][k]) / cov[p]
//
// R1: direct global atomics  -> 1178 us (fabric atomics, 732 MB writes)
// R2: counting-sort + gather -> 200 us
// R3: payload sort + stream  -> 184 us (ds_add_f32-bound accum)
// R5: accum in-LDS sort + reg accumulate -> 82 us (reorder dominant)
// R7: 16B bf16 records, 1 scattered store/sample -> 73 us (write amp ~2x:
//     every record its own partial line)
// R8: in-block sorted writes, runs 122 B < 128 B line -> neutral. Lesson:
//     only run-length vs L2-line matters, not in-block write order.
// R9: NBLK=256 -> runs ~488 B (~4 lines, amp ~1.26), reorder back to lean
//     unsorted 1-deep-pipelined loop (no LDS staging). Accum unchanged.
// ---------------------------------------------------------------------------

constexpr int NB   = 256;    // buckets
constexpr int BW   = 768;    // pixels per bucket (npix = NB*BW = 196608)
constexpr int NBLK = 256;    // chunking blocks for hist/reorder
constexpr int TILE = 2048;   // records per accum tile

// hist2d layout: [NBLK][NB]

__device__ __forceinline__ unsigned f2bf(float f) {
    unsigned u = __float_as_uint(f);
    unsigned r = ((u >> 16) & 1u) + 0x7fffu;   // round to nearest even
    return (u + r) >> 16;
}
__device__ __forceinline__ float bf_lo(unsigned u) {
    return __uint_as_float(u << 16);
}
__device__ __forceinline__ float bf_hi(unsigned u) {
    return __uint_as_float(u & 0xffff0000u);
}

// ---------------- sort infrastructure ----------------

__global__ __launch_bounds__(1024)
void hist_kernel(const int* __restrict__ pix, int S, int chunk,
                 int* __restrict__ hist2d) {
    __shared__ int lh[NB];
    if (threadIdx.x < NB) lh[threadIdx.x] = 0;
    __syncthreads();
    const int beg = blockIdx.x * chunk;
    const int end = min(S, beg + chunk);
    for (int j = beg + threadIdx.x; j < end; j += blockDim.x)
        atomicAdd(&lh[pix[j] / BW], 1);
    __syncthreads();
    if (threadIdx.x < NB)
        hist2d[(size_t)blockIdx.x * NB + threadIdx.x] = lh[threadIdx.x];
}

// one block per bucket: exclusive scan of its NBLK per-block counts
__global__ __launch_bounds__(NBLK)
void scan_blocks_kernel(int* __restrict__ hist2d,
                        int* __restrict__ btotal) {
    __shared__ int sc[NBLK];
    const int bkt = blockIdx.x, tid = threadIdx.x;
    const int v = hist2d[(size_t)tid * NB + bkt];
    sc[tid] = v;
    __syncthreads();
    for (int off = 1; off < NBLK; off <<= 1) {
        int x = (tid >= off) ? sc[tid - off] : 0;
        __syncthreads();
        sc[tid] += x;
        __syncthreads();
    }
    hist2d[(size_t)tid * NB + bkt] = sc[tid] - v;   // exclusive within bucket
    if (tid == NBLK - 1) btotal[bkt] = sc[tid];
}

// single block: exclusive scan of NB bucket totals
__global__ __launch_bounds__(NB)
void scan_buckets_kernel(const int* __restrict__ btotal,
                         int* __restrict__ bbase, int S) {
    __shared__ int sc[NB];
    const int tid = threadIdx.x;
    const int v = btotal[tid];
    sc[tid] = v;
    __syncthreads();
    for (int off = 1; off < NB; off <<= 1) {
        int x = (tid >= off) ? sc[tid - off] : 0;
        __syncthreads();
        sc[tid] += x;
        __syncthreads();
    }
    bbase[tid] = sc[tid] - v;
    if (tid == NB - 1) bbase[NB] = sc[tid];
}

// ---------------- R9 reorder: lean, unsorted, long per-block runs ----------
// record = {w0|w1, w2|lpix, t0|t1, t2|t3} packed bf16, 16 B
__global__ __launch_bounds__(1024)
void reorder_linear_kernel(const float* __restrict__ tod,     // [4][S]
                           const float* __restrict__ weights, // [S][3]
                           const int* __restrict__ pix,       // [S]
                           int S, int chunk,
                           const int* __restrict__ hist2d,
                           const int* __restrict__ bbase,
                           uint4* __restrict__ rec) {         // [S]
    __shared__ int lbase[NB];
    __shared__ int lcur[NB];
    const int blk = blockIdx.x;
    if (threadIdx.x < NB) {
        lbase[threadIdx.x] = bbase[threadIdx.x]
                           + hist2d[(size_t)blk * NB + threadIdx.x];
        lcur[threadIdx.x] = 0;
    }
    __syncthreads();
    const int beg = blk * chunk;
    const int end = min(S, beg + chunk);
    const int bs  = blockDim.x;

    int j = beg + (int)threadIdx.x;
    int p = 0;
    float w0 = 0, w1 = 0, w2 = 0, t0 = 0, t1 = 0, t2 = 0, t3 = 0;
    if (j < end) {
        p  = pix[j];
        w0 = weights[3 * j + 0]; w1 = weights[3 * j + 1]; w2 = weights[3 * j + 2];
        t0 = tod[(size_t)0 * S + j]; t1 = tod[(size_t)1 * S + j];
        t2 = tod[(size_t)2 * S + j]; t3 = tod[(size_t)3 * S + j];
    }
    while (j < end) {
        const int jn = j + bs;
        int pn = 0;
        float wn0 = 0, wn1 = 0, wn2 = 0, tn0 = 0, tn1 = 0, tn2 = 0, tn3 = 0;
        if (jn < end) {                       // issue next sample's loads early
            pn  = pix[jn];
            wn0 = weights[3 * jn + 0]; wn1 = weights[3 * jn + 1]; wn2 = weights[3 * jn + 2];
            tn0 = tod[(size_t)0 * S + jn]; tn1 = tod[(size_t)1 * S + jn];
            tn2 = tod[(size_t)2 * S + jn]; tn3 = tod[(size_t)3 * S + jn];
        }
        const int bkt = p / BW;               // magic-mul (BW constant)
        const int lp  = p - bkt * BW;
        const int r   = atomicAdd(&lcur[bkt], 1);        // LDS int atomic
        const int dst = lbase[bkt] + r;
        uint4 v;
        v.x = f2bf(w0) | (f2bf(w1) << 16);
        v.y = f2bf(w2) | ((unsigned)lp << 16);
        v.z = f2bf(t0) | (f2bf(t1) << 16);
        v.w = f2bf(t2) | (f2bf(t3) << 16);
        rec[dst] = v;                                    // ONE 16 B store
        j = jn; p = pn;
        w0 = wn0; w1 = wn1; w2 = wn2;
        t0 = tn0; t1 = tn1; t2 = tn2; t3 = tn3;
    }
}

// one block (1024 threads) per bucket (768 pixels). Per tile of <=2048:
//   stage records in LDS -> 768-bin counting sort (int LDS atomics) ->
//   thread (l=tid&255, q=tid>>8) walks pixels {l, l+256, l+512}, f32 regs.
__global__ __launch_bounds__(1024)
void accum_sort_kernel(const uint4* __restrict__ rec,    // [S]
                       const float* __restrict__ cov,    // [npix]
                       const int* __restrict__ bbase,    // [NB+1]
                       float* __restrict__ out,          // [4][npix][3]
                       int npix) {
    __shared__ uint4          lrec[TILE];      // 32 KB
    __shared__ unsigned short lpx[TILE];       //  4 KB
    __shared__ unsigned short lidx[TILE];      //  4 KB
    __shared__ int            start[BW + 1];
    __shared__ int            cur[BW];

    const int bkt = blockIdx.x;
    const int beg = bbase[bkt], end = bbase[bkt + 1];
    const int l = threadIdx.x & 255;
    const int q = threadIdx.x >> 8;            // wave-uniform
    float s00 = 0.f, s01 = 0.f, s02 = 0.f;
    float s10 = 0.f, s11 = 0.f, s12 = 0.f;
    float s20 = 0.f, s21 = 0.f, s22 = 0.f;

    for (int tbeg = beg; tbeg < end; tbeg += TILE) {
        const int n = min(TILE, end - tbeg);

        for (int t = threadIdx.x; t < BW; t += blockDim.x) cur[t] = 0;
        __syncthreads();
        for (int j = threadIdx.x; j < n; j += blockDim.x) {
            const uint4 r = rec[(size_t)(tbeg + j)];
            lrec[j] = r;
            const int lp = (int)(r.y >> 16);
            lpx[j] = (unsigned short)lp;
            atomicAdd(&cur[lp], 1);
        }
        __syncthreads();

        // wave 0: exclusive scan of BW=768 counts (12 bins/lane + shfl scan)
        if (threadIdx.x < 64) {
            const int i0 = threadIdx.x * 12;
            int v[12], pre[12], run = 0;
            #pragma unroll
            for (int k = 0; k < 12; ++k) {
                v[k] = cur[i0 + k]; pre[k] = run; run += v[k];
            }
            int x = run;
            #pragma unroll
            for (int off = 1; off < 64; off <<= 1) {
                const int y = __shfl_up(x, off, 64);
                if ((int)threadIdx.x >= off) x += y;
            }
            const int base = x - run;
            #pragma unroll
            for (int k = 0; k < 12; ++k) {
                start[i0 + k] = base + pre[k];
                cur[i0 + k]   = base + pre[k];
            }
            if (threadIdx.x == 63) start[BW] = base + run;
        }
        __syncthreads();

        for (int j = threadIdx.x; j < n; j += blockDim.x) {
            const int r = atomicAdd(&cur[lpx[j]], 1);
            lidx[r] = (unsigned short)j;
        }
        __syncthreads();

        // three statically-unrolled run walks (pixels l, l+256, l+512)
        {
            const int rb = start[l], re = start[l + 1];
            for (int j = rb; j < re; ++j) {
                const int i = lidx[j];
                const uint4 r = lrec[i];
                const float tq = (q == 0) ? bf_lo(r.z) : (q == 1) ? bf_hi(r.z)
                               : (q == 2) ? bf_lo(r.w) : bf_hi(r.w);
                s00 += tq * bf_lo(r.x);
                s01 += tq * bf_hi(r.x);
                s02 += tq * bf_lo(r.y);
            }
        }
        {
            const int rb = start[l + 256], re = start[l + 257];
            for (int j = rb; j < re; ++j) {
                const int i = lidx[j];
                const uint4 r = lrec[i];
                const float tq = (q == 0) ? bf_lo(r.z) : (q == 1) ? bf_hi(r.z)
                               : (q == 2) ? bf_lo(r.w) : bf_hi(r.w);
                s10 += tq * bf_lo(r.x);
                s11 += tq * bf_hi(r.x);
                s12 += tq * bf_lo(r.y);
            }
        }
        {
            const int rb = start[l + 512], re = start[l + 513];
            for (int j = rb; j < re; ++j) {
                const int i = lidx[j];
                const uint4 r = lrec[i];
                const float tq = (q == 0) ? bf_lo(r.z) : (q == 1) ? bf_hi(r.z)
                               : (q == 2) ? bf_lo(r.w) : bf_hi(r.w);
                s20 += tq * bf_lo(r.x);
                s21 += tq * bf_hi(r.x);
                s22 += tq * bf_lo(r.y);
            }
        }
        __syncthreads();
    }

    // fused coverage normalize + coalesced store (3 pixel groups)
    {
        const int p = bkt * BW + l;
        const float rc = 1.0f / cov[p];
        const size_t o = ((size_t)q * npix + p) * 3;
        out[o + 0] = s00 * rc; out[o + 1] = s01 * rc; out[o + 2] = s02 * rc;
    }
    {
        const int p = bkt * BW + 256 + l;
        const float rc = 1.0f / cov[p];
        const size_t o = ((size_t)q * npix + p) * 3;
        out[o + 0] = s10 * rc; out[o + 1] = s11 * rc; out[o + 2] = s12 * rc;
    }
    {
        const int p = bkt * BW + 512 + l;
        const float rc = 1.0f / cov[p];
        const size_t o = ((size_t)q * npix + p) * 3;
        out[o + 0] = s20 * rc; out[o + 1] = s21 * rc; out[o + 2] = s22 * rc;
    }
}

// ---------------- generic fallback: direct atomics -------------------------

__global__ void zero_out_kernel(float4* __restrict__ out, int n4) {
    int i = blockIdx.x * blockDim.x + threadIdx.x;
    int stride = gridDim.x * blockDim.x;
    for (; i < n4; i += stride) out[i] = make_float4(0.f, 0.f, 0.f, 0.f);
}

__global__ void scatter_kernel(const float* __restrict__ tod,
                               const float* __restrict__ weights,
                               const int*   __restrict__ pix,
                               float* __restrict__ out,
                               int S, int npix, int B) {
    int i = blockIdx.x * blockDim.x + threadIdx.x;
    int stride = gridDim.x * blockDim.x;
    const size_t bstride = (size_t)npix * 3;
    for (int s = i; s < S; s += stride) {
        const int p = pix[s];
        const float w0 = weights[3 * s + 0];
        const float w1 = weights[3 * s + 1];
        const float w2 = weights[3 * s + 2];
        float* o = out + (size_t)p * 3;
        for (int b = 0; b < B; ++b) {
            const float t = tod[(size_t)b * S + s];
            float* ob = o + (size_t)b * bstride;
            atomicAdd(ob + 0, t * w0);
            atomicAdd(ob + 1, t * w1);
            atomicAdd(ob + 2, t * w2);
        }
    }
}

__global__ void normalize_kernel(float* __restrict__ out,
                                 const float* __restrict__ cov,
                                 int npix, int B) {
    int i = blockIdx.x * blockDim.x + threadIdx.x;
    int stride = gridDim.x * blockDim.x;
    const int total = B * npix;
    for (; i < total; i += stride) {
        const int p = i % npix;
        const float c = cov[p];
        float* o = out + (size_t)i * 3;
        o[0] /= c; o[1] /= c; o[2] /= c;
    }
}

// ---------------- launch ----------------

extern "C" void kernel_launch(void* const* d_in, const int* in_sizes, int n_in,
                              void* d_out, int out_size, void* d_ws, size_t ws_size,
                              hipStream_t stream) {
    const float* tod     = (const float*)d_in[0];   // [B][S]
    const float* weights = (const float*)d_in[1];   // [S][3]
    const float* cov     = (const float*)d_in[2];   // [NPIX]
    const int*   pix     = (const int*)d_in[3];     // [S]
    float* out = (float*)d_out;                     // [B][NPIX][3]

    const int S    = in_sizes[3];
    const int npix = in_sizes[2];
    const int B    = in_sizes[0] / S;

    const size_t meta_ints  = (size_t)NB * NBLK + NB + (NB + 1);
    const size_t meta_bytes = ((meta_ints * sizeof(int)) + 63) & ~(size_t)63;
    const size_t need_rec   = meta_bytes + (size_t)S * 16;

    const int chunk = (S + NBLK - 1) / NBLK;

    if (B == 4 && npix == NB * BW && ws_size >= need_rec) {
        int* hist2d = (int*)d_ws;                   // [NBLK][NB]
        int* btotal = hist2d + (size_t)NB * NBLK;
        int* bbase  = btotal + NB;
        uint4* rec  = (uint4*)((char*)d_ws + meta_bytes);

        hist_kernel<<<NBLK, 1024, 0, stream>>>(pix, S, chunk, hist2d);
        scan_blocks_kernel<<<NB, NBLK, 0, stream>>>(hist2d, btotal);
        scan_buckets_kernel<<<1, NB, 0, stream>>>(btotal, bbase, S);
        reorder_linear_kernel<<<NBLK, 1024, 0, stream>>>(tod, weights, pix, S,
                                                         chunk, hist2d, bbase, rec);
        accum_sort_kernel<<<NB, 1024, 0, stream>>>(rec, cov, bbase, out, npix);
        return;
    }

    // ---- generic fallback ----
    const int block = 256;
    {
        const int n4 = out_size / 4;
        int grid = min((n4 + block - 1) / block, 2048);
        zero_out_kernel<<<grid, block, 0, stream>>>((float4*)out, n4);
    }
    {
        int grid = min((S + block - 1) / block, 4096);
        scatter_kernel<<<grid, block, 0, stream>>>(tod, weights, pix, out, S, npix, B);
    }
    {
        const int total = B * npix;
        int grid = min((total + block - 1) / block, 2048);
        normalize_kernel<<<grid, block, 0, stream>>>(out, cov, npix, B);
    }
}